// Round 14
// baseline (89.237 us; speedup 1.0000x reference)
//
#include <hip/hip_runtime.h>
#include <hip/hip_bf16.h>

#define NSPK 1024
#define MU 32
#define DIM 512
#define DIMP (DIM + 8)
#define NROW (NSPK * MU)   // 32768
#define EPS 1e-6f

typedef __attribute__((ext_vector_type(4))) float f32x4;
typedef __attribute__((ext_vector_type(8))) short bf16x8;

#define GLOAD_LDS16(g, l)                                          \
  __builtin_amdgcn_global_load_lds(                                \
      (const __attribute__((address_space(1))) void*)(g),          \
      (__attribute__((address_space(3))) void*)(l), 16, 0, 0)

__device__ inline ushort f2bf(float x) {
  __hip_bfloat16 h = __float2bfloat16(x);
  return *reinterpret_cast<ushort*>(&h);
}

// ---------------------------------------------------------------------------
// Kernel 1: per-speaker prep. LOO cosines (fp32 exact) + normalized bf16
// A and B written in MFMA-FRAGMENT-MAJOR layout:
//   frag(rb16,kf) [A] / frag(nb16,kf) [B] = 512 ushorts; lane l holds
//   row/col = base16 + (l&15), k = kf*32 + (l>>4)*8 .. +8   (16 B chunk)
// grid = NSPK, block = 256   (unchanged since R2; verified)
// ---------------------------------------------------------------------------
__global__ __launch_bounds__(256) void k_prep(
    const float* __restrict__ dvecs,
    ushort* __restrict__ Af,    // [2048 rb16][16 kf][64 lane][8]
    ushort* __restrict__ Bf,    // [64 nb16][16 kf][64 lane][8]
    float* __restrict__ loo)    // [NROW]
{
  const int j = blockIdx.x, t = threadIdx.x;
  __shared__ float sD[MU * DIMP];   // padded raw speaker rows (66.5 KiB)
  __shared__ float sS[DIM];
  __shared__ float sred[4];
  __shared__ float sS2v;
  __shared__ float sInv[MU];

  const float* base = dvecs + (size_t)j * (MU * DIM);

  // single global read: stage rows + column sums
  float s0 = 0.f, s1 = 0.f;
  for (int m = 0; m < MU; ++m) {
    float a = base[m * DIM + t];
    float b = base[m * DIM + t + 256];
    sD[m * DIMP + t] = a;
    sD[m * DIMP + t + 256] = b;
    s0 += a; s1 += b;
  }
  sS[t] = s0; sS[t + 256] = s1;
  __syncthreads();

  // |S|^2
  float p = s0 * s0 + s1 * s1;
  for (int off = 32; off; off >>= 1) p += __shfl_down(p, off);
  if ((t & 63) == 0) sred[t >> 6] = p;
  __syncthreads();
  if (t == 0) sS2v = sred[0] + sred[1] + sred[2] + sred[3];
  __syncthreads();
  const float S2 = sS2v;

  // per-utterance dot(e,S), |e|^2 from LDS (8 lanes per row)
  const int g = t >> 3, l = t & 7;
  float dotS = 0.f, e2 = 0.f;
  for (int i = 0; i < DIM / 8; ++i) {
    int d = i * 8 + l;
    float ev = sD[g * DIMP + d];
    dotS += ev * sS[d];
    e2 += ev * ev;
  }
  for (int off = 4; off; off >>= 1) {
    dotS += __shfl_down(dotS, off);
    e2 += __shfl_down(e2, off);
  }
  if (l == 0) {
    float numer = dotS - e2;                          // e.(S-e)
    float d2 = fmaxf(S2 - 2.f * dotS + e2, 1e-30f);   // |S-e|^2
    loo[j * MU + g] = numer / (sqrtf(e2) * sqrtf(d2));
    sInv[g] = 1.f / sqrtf(e2);
  }
  __syncthreads();

  // A fragments: this speaker = rows j*32..+31 = rb16 j*2, j*2+1
  for (int i = 0; i < 8; ++i) {
    int idx = i * 256 + t;          // 0..2047 16B-chunks
    int fragL = idx >> 6;           // 0..31 (rbl*16 + kf)
    int lane2 = idx & 63;
    int rbl = fragL >> 4, kf = fragL & 15;
    int m = rbl * 16 + (lane2 & 15);
    int k0 = kf * 32 + (lane2 >> 4) * 8;
    float inv = sInv[m];
    ushort tmp[8];
#pragma unroll
    for (int z = 0; z < 8; ++z) tmp[z] = f2bf(sD[m * DIMP + k0 + z] * inv);
    *(bf16x8*)&Af[(((size_t)(j * 2 + rbl) * 16 + kf) << 9) + lane2 * 8] =
        *(bf16x8*)tmp;
  }

  // B fragment pieces for centroid j (col j -> lane&15 = j&15)
  if (t < 64) {
    int kf = t >> 2, q = t & 3;
    int lane2 = q * 16 + (j & 15);
    float invc = 1.f / sqrtf(S2);
    int k0 = kf * 32 + q * 8;
    ushort tmp[8];
#pragma unroll
    for (int z = 0; z < 8; ++z) tmp[z] = f2bf(sS[k0 + z] * invc);
    *(bf16x8*)&Bf[(((size_t)(j >> 4) * 16 + kf) << 9) + lane2 * 8] =
        *(bf16x8*)tmp;
  }
}

// ---------------------------------------------------------------------------
// Kernel 2: 128x256 tile, 3-buffer counted-vmcnt pipelined GEMM.
// 256 thr (4 waves, 2wm x 2wn), wave tile 64x128: acc[4][8] = 128 regs --
// R7's register shape (236 VGPR, no spill at 256 thr). BK=32, 16 K-steps.
// R13 post-mortem: per-CU step cost ~940cyc vs ~300cyc useful -- the
// per-step sync scaffolding dominates at 128x128. This tile doubles
// per-step work (32 MFMA + 12 KB ds_read per wave, 0.375 KB/MFMA = m201's
// ratio) and halves per-CU step count; staging drops 512->384 MB.
// Schedule = R12's (proven): counted vmcnt(6) consume-wait (6 stage
// loads/thread/step; prologue 12 in flight), raw s_barrier, STAGE(kt+2),
// ds_read + MFMA (setprio), lgkmcnt(0) buffer safety (rule #18).
// LDS 73 KiB -> 2 blocks/CU; ~210 VGPR -> 2 waves/SIMD.
// Grid 1024 = 256 rb x 4 cb, XCD-chunked swizzle (32-rb band per XCD:
// 4 MB A + 1 MB B per XCD ~ L2-resident).
// ---------------------------------------------------------------------------
__global__ __launch_bounds__(256, 1) void k_gemm(
    const ushort* __restrict__ Af,
    const ushort* __restrict__ Bf,
    const float* __restrict__ wp,
    float* __restrict__ part,    // [4][NROW] partial sumexp per col-chunk
    float* __restrict__ diag)    // [NROW] raw cos vs own full centroid
{
  __shared__ ushort ldsA[3 * 8 * 512];    // 24 KiB: 3 bufs x 8 frags
  __shared__ ushort ldsB[3 * 16 * 512];   // 48 KiB: 3 bufs x 16 frags
  __shared__ float sPart[128][2];         // 1 KiB

  const int t = threadIdx.x;
  const int w = t >> 6, lane = t & 63;
  const int lr = lane & 15, lk = lane >> 4;
  const int wm = w >> 1, wn = w & 1;      // 2 x 2 wave grid
  // XCD-chunked block swizzle (HW: consecutive bids round-robin XCDs)
  const int bid = blockIdx.x;
  const int xcd = bid & 7, ii = bid >> 3;     // ii in [0,128) per XCD
  const int rb = xcd * 32 + (ii >> 2);        // 0..255 (128 rows each)
  const int cb = ii & 3;                      // 0..3   (256 cols each)

  f32x4 acc[4][8];
#pragma unroll
  for (int a = 0; a < 4; ++a)
#pragma unroll
    for (int b = 0; b < 8; ++b) acc[a][b] = (f32x4)0.f;

  // hoisted per-thread staging bases (ushort units); step offset = kt*512
  const ushort* gA0 = Af + (((size_t)(rb * 8 + w) * 16) << 9) + lane * 8;
  const ushort* gA1 = Af + (((size_t)(rb * 8 + w + 4) * 16) << 9) + lane * 8;
  const ushort* gB0 = Bf + (((size_t)(cb * 16 + w) * 16) << 9) + lane * 8;
  const ushort* gB1 = Bf + (((size_t)(cb * 16 + w + 4) * 16) << 9) + lane * 8;
  const ushort* gB2 = Bf + (((size_t)(cb * 16 + w + 8) * 16) << 9) + lane * 8;
  const ushort* gB3 = Bf + (((size_t)(cb * 16 + w + 12) * 16) << 9) + lane * 8;
  ushort* dA0 = &ldsA[w * 512 + lane * 8];
  ushort* dA1 = &ldsA[(w + 4) * 512 + lane * 8];
  ushort* dB0 = &ldsB[w * 512 + lane * 8];
  ushort* dB1 = &ldsB[(w + 4) * 512 + lane * 8];
  ushort* dB2 = &ldsB[(w + 8) * 512 + lane * 8];
  ushort* dB3 = &ldsB[(w + 12) * 512 + lane * 8];

#define STAGE(kt, bi)                                   \
  {                                                     \
    GLOAD_LDS16(gA0 + (kt) * 512, dA0 + (bi) * 4096);   \
    GLOAD_LDS16(gA1 + (kt) * 512, dA1 + (bi) * 4096);   \
    GLOAD_LDS16(gB0 + (kt) * 512, dB0 + (bi) * 8192);   \
    GLOAD_LDS16(gB1 + (kt) * 512, dB1 + (bi) * 8192);   \
    GLOAD_LDS16(gB2 + (kt) * 512, dB2 + (bi) * 8192);   \
    GLOAD_LDS16(gB3 + (kt) * 512, dB3 + (bi) * 8192);   \
  }

  // fragment read bases
  const ushort* lA0 = &ldsA[(wm * 4) * 512 + lane * 8];
  const ushort* lB0 = &ldsB[(wn * 8) * 512 + lane * 8];

  // ---- prologue: 2-deep prefetch (12 loads/thread in flight) ----
  STAGE(0, 0);
  STAGE(1, 1);

  // ---- pipelined K-loop ----
#pragma unroll
  for (int kt = 0; kt < 16; ++kt) {
    if (kt < 15) {
      asm volatile("s_waitcnt vmcnt(6)" ::: "memory");  // stage(kt) landed
    } else {
      asm volatile("s_waitcnt vmcnt(0)" ::: "memory");
    }
    __builtin_amdgcn_s_barrier();
    __builtin_amdgcn_sched_barrier(0);

    if (kt <= 13) STAGE(kt + 2, (kt + 2) % 3);

    const ushort* lA = lA0 + (kt % 3) * 4096;
    const ushort* lB = lB0 + (kt % 3) * 8192;
    bf16x8 afr[4], bfr[8];
#pragma unroll
    for (int nf = 0; nf < 8; ++nf)
      bfr[nf] = *(const bf16x8*)(lB + nf * 512);
#pragma unroll
    for (int mf = 0; mf < 4; ++mf)
      afr[mf] = *(const bf16x8*)(lA + mf * 512);

    __builtin_amdgcn_s_setprio(1);
#pragma unroll
    for (int mf = 0; mf < 4; ++mf)
#pragma unroll
      for (int nf = 0; nf < 8; ++nf)
        acc[mf][nf] = __builtin_amdgcn_mfma_f32_16x16x32_bf16(
            afr[mf], bfr[nf], acc[mf][nf], 0, 0, 0);
    __builtin_amdgcn_s_setprio(0);

    if (kt < 15) {
      asm volatile("s_waitcnt lgkmcnt(0)" ::: "memory");  // buf safety
      __builtin_amdgcn_sched_barrier(0);
    }
  }
#undef STAGE

  const float W = *wp;

  // ---- diag capture (raw cos) before exp consumes acc ----
  // block rows = speakers rb*4..+3; col c = rb*4+sp in this block iff
  // cb == c>>8 (= rb>>6, no carry since sp<4).
  if (cb == (rb >> 6)) {
#pragma unroll
    for (int sp = 0; sp < 4; ++sp) {
      const int c = rb * 4 + sp;
      if (wm == (sp >> 1) && wn == ((c >> 7) & 1)) {
        const int nfo = (c >> 4) & 7;
#pragma unroll
        for (int mh = 0; mh < 2; ++mh) {
          f32x4 dsel = acc[(sp & 1) * 2 + mh][0];
#pragma unroll
          for (int nf = 1; nf < 8; ++nf)
            if (nf == nfo) dsel = acc[(sp & 1) * 2 + mh][nf];  // static idx
          if (lr == (c & 15)) {
#pragma unroll
            for (int i = 0; i < 4; ++i)
              diag[c * 32 + mh * 16 + lk * 4 + i] = dsel[i];
          }
        }
      }
    }
  }

  // ---- fused epilogue: exp((fmax(cos,eps)-1)*W), reduce over 128 cols ----
#pragma unroll
  for (int mf = 0; mf < 4; ++mf)
#pragma unroll
    for (int i = 0; i < 4; ++i) {
      float s = 0.f;
#pragma unroll
      for (int nf = 0; nf < 8; ++nf)
        s += __expf((fmaxf(acc[mf][nf][i], EPS) - 1.f) * W);
      s += __shfl_xor(s, 1);
      s += __shfl_xor(s, 2);
      s += __shfl_xor(s, 4);
      s += __shfl_xor(s, 8);
      if (lr == 0) sPart[wm * 64 + mf * 16 + lk * 4 + i][wn] = s;
    }
  __syncthreads();
  if (t < 128)
    part[(size_t)cb * NROW + rb * 128 + t] = sPart[t][0] + sPart[t][1];
}

// ---------------------------------------------------------------------------
// Final: sum 4 col-chunk partials, swap exp(diag)->exp(loo), close lse,
// deterministic 2-stage sum.  L_row = log(s - exp(dt) + exp(lt)) - lt
// ---------------------------------------------------------------------------
__global__ __launch_bounds__(256) void k_final1(
    const float* __restrict__ part, const float* __restrict__ loo,
    const float* __restrict__ diag, const float* __restrict__ wp,
    float* __restrict__ p2)
{
  const int t = threadIdx.x;
  const int r = blockIdx.x * 256 + t;
  const float W = *wp;
  float s = 0.f;
#pragma unroll
  for (int c = 0; c < 4; ++c) s += part[(size_t)c * NROW + r];
  const float lt = (fmaxf(loo[r], EPS) - 1.f) * W;
  const float dt = (fmaxf(diag[r], EPS) - 1.f) * W;
  s += __expf(lt) - __expf(dt);
  float v = logf(s) - lt;
  __shared__ float red[4];
  for (int off = 32; off; off >>= 1) v += __shfl_down(v, off);
  if ((t & 63) == 0) red[t >> 6] = v;
  __syncthreads();
  if (t == 0) p2[blockIdx.x] = red[0] + red[1] + red[2] + red[3];
}

__global__ __launch_bounds__(128) void k_final2(
    const float* __restrict__ p2, float* __restrict__ out)
{
  const int t = threadIdx.x;
  float v = p2[t];
  for (int off = 32; off; off >>= 1) v += __shfl_down(v, off);
  __shared__ float red[2];
  if ((t & 63) == 0) red[t >> 6] = v;
  __syncthreads();
  if (t == 0) out[0] = red[0] + red[1];
}

extern "C" void kernel_launch(void* const* d_in, const int* in_sizes, int n_in,
                              void* d_out, int out_size, void* d_ws, size_t ws_size,
                              hipStream_t stream) {
  const float* dvecs = (const float*)d_in[0];
  const float* wptr  = (const float*)d_in[1];
  // b cancels algebraically (shift = w+b subtracted and re-added) -> unused
  float* out = (float*)d_out;

  char* ws = (char*)d_ws;
  ushort* Af = (ushort*)ws;  ws += (size_t)NROW * DIM * sizeof(ushort); // 32 MiB
  ushort* Bf = (ushort*)ws;  ws += (size_t)NSPK * DIM * sizeof(ushort); // 1 MiB
  float* loo  = (float*)ws;  ws += (size_t)NROW * sizeof(float);
  float* diag = (float*)ws;  ws += (size_t)NROW * sizeof(float);
  float* part = (float*)ws;  ws += (size_t)4 * NROW * sizeof(float);    // 512 KiB
  float* p2   = (float*)ws;

  k_prep<<<NSPK, 256, 0, stream>>>(dvecs, Af, Bf, loo);
  k_gemm<<<1024, 256, 0, stream>>>(Af, Bf, wptr, part, diag);
  k_final1<<<NROW / 256, 256, 0, stream>>>(part, loo, diag, wptr, p2);
  k_final2<<<1, 128, 0, stream>>>(p2, out);
}

// Round 15
// 75.476 us; speedup vs baseline: 1.1823x; 1.1823x over previous
//
#include <hip/hip_runtime.h>
#include <hip/hip_bf16.h>

#define NSPK 1024
#define MU 32
#define DIM 512
#define DIMP (DIM + 8)
#define NROW (NSPK * MU)   // 32768
#define EPS 1e-6f

typedef __attribute__((ext_vector_type(4))) float f32x4;
typedef __attribute__((ext_vector_type(8))) short bf16x8;

#define GLOAD_LDS16(g, l)                                          \
  __builtin_amdgcn_global_load_lds(                                \
      (const __attribute__((address_space(1))) void*)(g),          \
      (__attribute__((address_space(3))) void*)(l), 16, 0, 0)

__device__ inline ushort f2bf(float x) {
  __hip_bfloat16 h = __float2bfloat16(x);
  return *reinterpret_cast<ushort*>(&h);
}

// ---------------------------------------------------------------------------
// Kernel 1: per-speaker prep. LOO cosines (fp32 exact) + normalized bf16
// A and B written in MFMA-FRAGMENT-MAJOR layout:
//   frag(rb16,kf) [A] / frag(nb16,kf) [B] = 512 ushorts; lane l holds
//   row/col = base16 + (l&15), k = kf*32 + (l>>4)*8 .. +8   (16 B chunk)
// grid = NSPK, block = 256   (unchanged since R2; verified)
// ---------------------------------------------------------------------------
__global__ __launch_bounds__(256) void k_prep(
    const float* __restrict__ dvecs,
    ushort* __restrict__ Af,    // [2048 rb16][16 kf][64 lane][8]
    ushort* __restrict__ Bf,    // [64 nb16][16 kf][64 lane][8]
    float* __restrict__ loo)    // [NROW]
{
  const int j = blockIdx.x, t = threadIdx.x;
  __shared__ float sD[MU * DIMP];   // padded raw speaker rows (66.5 KiB)
  __shared__ float sS[DIM];
  __shared__ float sred[4];
  __shared__ float sS2v;
  __shared__ float sInv[MU];

  const float* base = dvecs + (size_t)j * (MU * DIM);

  // single global read: stage rows + column sums
  float s0 = 0.f, s1 = 0.f;
  for (int m = 0; m < MU; ++m) {
    float a = base[m * DIM + t];
    float b = base[m * DIM + t + 256];
    sD[m * DIMP + t] = a;
    sD[m * DIMP + t + 256] = b;
    s0 += a; s1 += b;
  }
  sS[t] = s0; sS[t + 256] = s1;
  __syncthreads();

  // |S|^2
  float p = s0 * s0 + s1 * s1;
  for (int off = 32; off; off >>= 1) p += __shfl_down(p, off);
  if ((t & 63) == 0) sred[t >> 6] = p;
  __syncthreads();
  if (t == 0) sS2v = sred[0] + sred[1] + sred[2] + sred[3];
  __syncthreads();
  const float S2 = sS2v;

  // per-utterance dot(e,S), |e|^2 from LDS (8 lanes per row)
  const int g = t >> 3, l = t & 7;
  float dotS = 0.f, e2 = 0.f;
  for (int i = 0; i < DIM / 8; ++i) {
    int d = i * 8 + l;
    float ev = sD[g * DIMP + d];
    dotS += ev * sS[d];
    e2 += ev * ev;
  }
  for (int off = 4; off; off >>= 1) {
    dotS += __shfl_down(dotS, off);
    e2 += __shfl_down(e2, off);
  }
  if (l == 0) {
    float numer = dotS - e2;                          // e.(S-e)
    float d2 = fmaxf(S2 - 2.f * dotS + e2, 1e-30f);   // |S-e|^2
    loo[j * MU + g] = numer / (sqrtf(e2) * sqrtf(d2));
    sInv[g] = 1.f / sqrtf(e2);
  }
  __syncthreads();

  // A fragments: this speaker = rows j*32..+31 = rb16 j*2, j*2+1
  for (int i = 0; i < 8; ++i) {
    int idx = i * 256 + t;          // 0..2047 16B-chunks
    int fragL = idx >> 6;           // 0..31 (rbl*16 + kf)
    int lane2 = idx & 63;
    int rbl = fragL >> 4, kf = fragL & 15;
    int m = rbl * 16 + (lane2 & 15);
    int k0 = kf * 32 + (lane2 >> 4) * 8;
    float inv = sInv[m];
    ushort tmp[8];
#pragma unroll
    for (int z = 0; z < 8; ++z) tmp[z] = f2bf(sD[m * DIMP + k0 + z] * inv);
    *(bf16x8*)&Af[(((size_t)(j * 2 + rbl) * 16 + kf) << 9) + lane2 * 8] =
        *(bf16x8*)tmp;
  }

  // B fragment pieces for centroid j (col j -> lane&15 = j&15)
  if (t < 64) {
    int kf = t >> 2, q = t & 3;
    int lane2 = q * 16 + (j & 15);
    float invc = 1.f / sqrtf(S2);
    int k0 = kf * 32 + q * 8;
    ushort tmp[8];
#pragma unroll
    for (int z = 0; z < 8; ++z) tmp[z] = f2bf(sS[k0 + z] * invc);
    *(bf16x8*)&Bf[(((size_t)(j >> 4) * 16 + kf) << 9) + lane2 * 8] =
        *(bf16x8*)tmp;
  }
}

// ---------------------------------------------------------------------------
// Kernel 2: 4-buffer counted-vmcnt/lgkmcnt pipelined GEMM (no hard drains).
// Tile 128x128, BK=32 (16 K-steps), 256 thr (4 waves, 2wm x 2wn), wave
// tile 64x64 (acc[4][4] = 64 AGPR; arch ~110 -> 2 waves/SIMD).
// R13 post-mortem: the end-of-step lgkmcnt(0) made every wave eat the full
// shared-LDS queue latency (~1150cyc/CU) every step -> pipes serialized
// (step-round 2800cyc ~= LDS+L2+MFMA summed). This round removes ALL
// lgkm(0) drains: 4 LDS buffers give 2 iterations of write-after-read
// slack, so buffer safety needs only each wave's counted lgkmcnt(8)
// (before MFMA, covering reads issued a FULL iteration earlier) +
// the barrier. Safety chain: sibling DSREAD(kt-1) <= sibling lgkmcnt(8)
// @iter kt-1 < sibling barrier-arrival @iter kt < my STAGE(kt+3) which
// writes buf[(kt+3)&3] = buf[(kt-1)&3]. vmcnt ledger: prologue stages
// 0,1,2 (12 loads); iter kt waits vmcnt(4) = stage(kt+1) landed (its
// DSREAD happens this iter), leaves stage(kt+2) in flight.
// LDS 4x16 KiB + 1 = 65 KiB -> 2 blocks/CU.
// Grid 2048 = 256 rb x 8 cb, XCD-chunked swizzle (32-rb band per XCD).
// ---------------------------------------------------------------------------
__global__ __launch_bounds__(256, 1) void k_gemm(
    const ushort* __restrict__ Af,
    const ushort* __restrict__ Bf,
    const float* __restrict__ wp,
    float* __restrict__ part,    // [8][NROW] partial sumexp per col-chunk
    float* __restrict__ diag)    // [NROW] raw cos vs own full centroid
{
  __shared__ ushort ldsA[4 * 8 * 512];    // 32 KiB: 4 bufs x 8 frags
  __shared__ ushort ldsB[4 * 8 * 512];    // 32 KiB
  __shared__ float sPart[128][2];         // 1 KiB

  const int t = threadIdx.x;
  const int w = t >> 6, lane = t & 63;
  const int lr = lane & 15, lk = lane >> 4;
  const int wm = w >> 1, wn = w & 1;      // 2 x 2 wave grid
  // XCD-chunked block swizzle (HW: consecutive bids round-robin XCDs)
  const int bid = blockIdx.x;
  const int xcd = bid & 7, ii = bid >> 3;     // ii in [0,256) per XCD
  const int rb = xcd * 32 + (ii >> 3);        // 0..255 (128 rows each)
  const int cb = ii & 7;                      // 0..7   (128 cols each)

  f32x4 acc[4][4];
#pragma unroll
  for (int a = 0; a < 4; ++a)
#pragma unroll
    for (int b = 0; b < 4; ++b) acc[a][b] = (f32x4)0.f;

  // hoisted per-thread staging bases (ushort units); step offset = kt*512
  const ushort* gA0 = Af + (((size_t)(rb * 8 + w) * 16) << 9) + lane * 8;
  const ushort* gA1 = Af + (((size_t)(rb * 8 + w + 4) * 16) << 9) + lane * 8;
  const ushort* gB0 = Bf + (((size_t)(cb * 8 + w) * 16) << 9) + lane * 8;
  const ushort* gB1 = Bf + (((size_t)(cb * 8 + w + 4) * 16) << 9) + lane * 8;
  ushort* dA0 = &ldsA[w * 512 + lane * 8];
  ushort* dA1 = &ldsA[(w + 4) * 512 + lane * 8];
  ushort* dB0 = &ldsB[w * 512 + lane * 8];
  ushort* dB1 = &ldsB[(w + 4) * 512 + lane * 8];

#define STAGE(kt, bi)                                   \
  {                                                     \
    GLOAD_LDS16(gA0 + (kt) * 512, dA0 + (bi) * 4096);   \
    GLOAD_LDS16(gA1 + (kt) * 512, dA1 + (bi) * 4096);   \
    GLOAD_LDS16(gB0 + (kt) * 512, dB0 + (bi) * 4096);   \
    GLOAD_LDS16(gB1 + (kt) * 512, dB1 + (bi) * 4096);   \
  }

  // fragment register double-buffer; indices static under full unroll
  bf16x8 afr[2][4], bfr[2][4];
  const ushort* lA0 = &ldsA[(wm * 4) * 512 + lane * 8];
  const ushort* lB0 = &ldsB[(wn * 4) * 512 + lane * 8];

#define DSREAD(set, bi)                                                   \
  {                                                                       \
    _Pragma("unroll")                                                     \
    for (int nf = 0; nf < 4; ++nf)                                        \
      bfr[set][nf] = *(const bf16x8*)(lB0 + (bi) * 4096 + nf * 512);      \
    _Pragma("unroll")                                                     \
    for (int mf = 0; mf < 4; ++mf)                                        \
      afr[set][mf] = *(const bf16x8*)(lA0 + (bi) * 4096 + mf * 512);      \
  }

  // ---- prologue: 3-deep stage prefetch (12 loads/thread in flight) ----
  STAGE(0, 0);
  STAGE(1, 1);
  STAGE(2, 2);
  asm volatile("s_waitcnt vmcnt(8)" ::: "memory");   // stage(0) landed
  __builtin_amdgcn_s_barrier();
  __builtin_amdgcn_sched_barrier(0);
  DSREAD(0, 0);                                      // step-0 frags

  // ---- pipelined K-loop: no lgkm(0) drains inside ----
#pragma unroll
  for (int kt = 0; kt < 16; ++kt) {
    // stage(kt+1) landed (its DSREAD is this iter); stage(kt+2) in flight
    if (kt < 14) {
      asm volatile("s_waitcnt vmcnt(4)" ::: "memory");
    } else {
      asm volatile("s_waitcnt vmcnt(0)" ::: "memory");
    }
    __builtin_amdgcn_s_barrier();
    __builtin_amdgcn_sched_barrier(0);

    if (kt <= 12) STAGE(kt + 3, (kt + 3) & 3);       // overwrites buf[(kt-1)&3]
    if (kt < 15) DSREAD((kt + 1) & 1, (kt + 1) & 3); // no wait; overlaps MFMA

    // counted wait: DSREAD(kt) done (issued a full iter ago);
    // DSREAD(kt+1)'s 8 reads stay outstanding.
    if (kt < 15) {
      asm volatile("s_waitcnt lgkmcnt(8)" ::: "memory");
    } else {
      asm volatile("s_waitcnt lgkmcnt(0)" ::: "memory");
    }
    __builtin_amdgcn_sched_barrier(0);

    __builtin_amdgcn_s_setprio(1);
#pragma unroll
    for (int mf = 0; mf < 4; ++mf)
#pragma unroll
      for (int nf = 0; nf < 4; ++nf)
        acc[mf][nf] = __builtin_amdgcn_mfma_f32_16x16x32_bf16(
            afr[kt & 1][mf], bfr[kt & 1][nf], acc[mf][nf], 0, 0, 0);
    __builtin_amdgcn_s_setprio(0);
  }
#undef STAGE
#undef DSREAD

  const float W = *wp;

  // ---- diag capture (raw cos) before exp consumes acc ----
  // block rows = speakers rb*4..+3; col c = rb*4+sp in this block iff
  // cb == c>>7 (= rb>>5, no carry since sp<4).
  if (cb == (rb >> 5)) {
#pragma unroll
    for (int sp = 0; sp < 4; ++sp) {
      const int c = rb * 4 + sp;
      if (wm == (sp >> 1) && wn == ((c >> 6) & 1)) {
        const int nfo = (c >> 4) & 3;
#pragma unroll
        for (int mh = 0; mh < 2; ++mh) {
          f32x4 dsel = acc[(sp & 1) * 2 + mh][0];
#pragma unroll
          for (int nf = 1; nf < 4; ++nf)
            if (nf == nfo) dsel = acc[(sp & 1) * 2 + mh][nf];  // static idx
          if (lr == (c & 15)) {
#pragma unroll
            for (int i = 0; i < 4; ++i)
              diag[c * 32 + mh * 16 + lk * 4 + i] = dsel[i];
          }
        }
      }
    }
  }

  // ---- fused epilogue: exp((fmax(cos,eps)-1)*W), reduce over 64 cols ----
#pragma unroll
  for (int mf = 0; mf < 4; ++mf)
#pragma unroll
    for (int i = 0; i < 4; ++i) {
      float s = 0.f;
#pragma unroll
      for (int nf = 0; nf < 4; ++nf)
        s += __expf((fmaxf(acc[mf][nf][i], EPS) - 1.f) * W);
      s += __shfl_xor(s, 1);
      s += __shfl_xor(s, 2);
      s += __shfl_xor(s, 4);
      s += __shfl_xor(s, 8);
      if (lr == 0) sPart[wm * 64 + mf * 16 + lk * 4 + i][wn] = s;
    }
  __syncthreads();
  if (t < 128)
    part[(size_t)cb * NROW + rb * 128 + t] = sPart[t][0] + sPart[t][1];
}

// ---------------------------------------------------------------------------
// Final: sum 8 col-chunk partials, swap exp(diag)->exp(loo), close lse,
// deterministic 2-stage sum.  L_row = log(s - exp(dt) + exp(lt)) - lt
// ---------------------------------------------------------------------------
__global__ __launch_bounds__(256) void k_final1(
    const float* __restrict__ part, const float* __restrict__ loo,
    const float* __restrict__ diag, const float* __restrict__ wp,
    float* __restrict__ p2)
{
  const int t = threadIdx.x;
  const int r = blockIdx.x * 256 + t;
  const float W = *wp;
  float s = 0.f;
#pragma unroll
  for (int c = 0; c < 8; ++c) s += part[(size_t)c * NROW + r];
  const float lt = (fmaxf(loo[r], EPS) - 1.f) * W;
  const float dt = (fmaxf(diag[r], EPS) - 1.f) * W;
  s += __expf(lt) - __expf(dt);
  float v = logf(s) - lt;
  __shared__ float red[4];
  for (int off = 32; off; off >>= 1) v += __shfl_down(v, off);
  if ((t & 63) == 0) red[t >> 6] = v;
  __syncthreads();
  if (t == 0) p2[blockIdx.x] = red[0] + red[1] + red[2] + red[3];
}

__global__ __launch_bounds__(128) void k_final2(
    const float* __restrict__ p2, float* __restrict__ out)
{
  const int t = threadIdx.x;
  float v = p2[t];
  for (int off = 32; off; off >>= 1) v += __shfl_down(v, off);
  __shared__ float red[2];
  if ((t & 63) == 0) red[t >> 6] = v;
  __syncthreads();
  if (t == 0) out[0] = red[0] + red[1];
}

extern "C" void kernel_launch(void* const* d_in, const int* in_sizes, int n_in,
                              void* d_out, int out_size, void* d_ws, size_t ws_size,
                              hipStream_t stream) {
  const float* dvecs = (const float*)d_in[0];
  const float* wptr  = (const float*)d_in[1];
  // b cancels algebraically (shift = w+b subtracted and re-added) -> unused
  float* out = (float*)d_out;

  char* ws = (char*)d_ws;
  ushort* Af = (ushort*)ws;  ws += (size_t)NROW * DIM * sizeof(ushort); // 32 MiB
  ushort* Bf = (ushort*)ws;  ws += (size_t)NSPK * DIM * sizeof(ushort); // 1 MiB
  float* loo  = (float*)ws;  ws += (size_t)NROW * sizeof(float);
  float* diag = (float*)ws;  ws += (size_t)NROW * sizeof(float);
  float* part = (float*)ws;  ws += (size_t)8 * NROW * sizeof(float);    // 1 MiB
  float* p2   = (float*)ws;

  k_prep<<<NSPK, 256, 0, stream>>>(dvecs, Af, Bf, loo);
  k_gemm<<<2048, 256, 0, stream>>>(Af, Bf, wptr, part, diag);
  k_final1<<<NROW / 256, 256, 0, stream>>>(part, loo, diag, wptr, p2);
  k_final2<<<1, 128, 0, stream>>>(p2, out);
}